// Round 2
// baseline (2170.515 us; speedup 1.0000x reference)
//
#include <hip/hip_runtime.h>
#include <math.h>

#define NUM_K 1024
#define DIM 256
#define HW 4096          // 64*64
#define NPIX 65536       // 16*4096
#define QELEMS 16777216  // 16*256*4096
#define MAX_FLAGS 16384

// ---------------------------------------------------------------------------
// numpy-replicated f32 sum of squares over 256 elements (pairwise, SIMD AVX512
// variant: two 128-blocks; per block 8x16-lane vertical tree, then gcc
// _mm512_reduce_add_ps horizontal tree; halves added in f32).
// All ops via __fmul_rn/__fadd_rn to forbid FMA contraction.
// ---------------------------------------------------------------------------
__device__ __forceinline__ float np_sumsq_256(const float* __restrict__ p, long stride) {
    float blk0 = 0.f, blk1 = 0.f;
#pragma unroll
    for (int h = 0; h < 2; ++h) {
        const float* base = p + (long)h * 128 * stride;
        float s[16];
#pragma unroll
        for (int L = 0; L < 16; ++L) {
            float a0 = base[(long)(L)       * stride]; a0 = __fmul_rn(a0, a0);
            float a1 = base[(long)(16 + L)  * stride]; a1 = __fmul_rn(a1, a1);
            float a2 = base[(long)(32 + L)  * stride]; a2 = __fmul_rn(a2, a2);
            float a3 = base[(long)(48 + L)  * stride]; a3 = __fmul_rn(a3, a3);
            float a4 = base[(long)(64 + L)  * stride]; a4 = __fmul_rn(a4, a4);
            float a5 = base[(long)(80 + L)  * stride]; a5 = __fmul_rn(a5, a5);
            float a6 = base[(long)(96 + L)  * stride]; a6 = __fmul_rn(a6, a6);
            float a7 = base[(long)(112 + L) * stride]; a7 = __fmul_rn(a7, a7);
            // ((r0+r1)+(r2+r3)) + ((r4+r5)+(r6+r7)) vertical per-lane
            float t1 = __fadd_rn(a0, a1);
            float t2 = __fadd_rn(a2, a3);
            float t3 = __fadd_rn(a4, a5);
            float t4 = __fadd_rn(a6, a7);
            s[L] = __fadd_rn(__fadd_rn(t1, t2), __fadd_rn(t3, t4));
        }
        // horizontal: c[L]=s[L]+s[L+8]; d[L]=c[L]+c[L+4]; (d0+d2)+(d1+d3)
        float c0 = __fadd_rn(s[0], s[8]);
        float c1 = __fadd_rn(s[1], s[9]);
        float c2 = __fadd_rn(s[2], s[10]);
        float c3 = __fadd_rn(s[3], s[11]);
        float c4 = __fadd_rn(s[4], s[12]);
        float c5 = __fadd_rn(s[5], s[13]);
        float c6 = __fadd_rn(s[6], s[14]);
        float c7 = __fadd_rn(s[7], s[15]);
        float d0 = __fadd_rn(c0, c4);
        float d1 = __fadd_rn(c1, c5);
        float d2 = __fadd_rn(c2, c6);
        float d3 = __fadd_rn(c3, c7);
        float e0 = __fadd_rn(d0, d2);
        float e1 = __fadd_rn(d1, d3);
        float r  = __fadd_rn(e0, e1);
        if (h == 0) blk0 = r; else blk1 = r;
    }
    return __fadd_rn(blk0, blk1);
}

// ---------- kernel 1: wsq[k] = np-f32 sum(w_k^2) ----------
__global__ __launch_bounds__(256) void k_wsq(const float* __restrict__ w, float* __restrict__ wsq) {
    int k = blockIdx.x * 256 + threadIdx.x;
    if (k < NUM_K) wsq[k] = np_sumsq_256(w + (long)k * DIM, 1);
}

// ---------- kernel 2: xsq[n] = np-f32 sum(x_n^2) (channel stride HW) ----------
__global__ __launch_bounds__(256) void k_xsq(const float* __restrict__ x, float* __restrict__ xsq) {
    int n = blockIdx.x * 256 + threadIdx.x;
    int b = n >> 12, hw = n & 4095;
    xsq[n] = np_sumsq_256(x + (long)b * DIM * HW + hw, HW);
}

// ---------- kernel 3: argmin over 1024 codes with np-f32 grid rounding ----------
// 256 threads = 4 waves; 64 pixels/block; wave q owns codes [q*256, q*256+256)
__global__ __launch_bounds__(256, 2)
void k_argmin(const float* __restrict__ x, const float* __restrict__ w,
              const float* __restrict__ wsq, const float* __restrict__ xsq,
              int* __restrict__ idx, int* __restrict__ flags, int* __restrict__ flag_count) {
    __shared__ float xs[64 * 257];
    __shared__ float sd1[4][64];
    __shared__ float sd2[4][64];
    __shared__ int   si1[4][64];

    const int t = threadIdx.x;
    const int p = t & 63;   // pixel in tile (== lane)
    const int q = t >> 6;   // wave id == code quarter
    const long n0 = (long)blockIdx.x * 64;
    const int b = (int)(n0 >> 12);
    const int hw0 = (int)(n0 & 4095);
    const float* xb = x + (long)b * DIM * HW + hw0;

    for (int i = 0; i < 64; ++i) {
        int c = q * 64 + i;
        xs[p * 257 + c] = xb[(long)c * HW + p];
    }
    __syncthreads();

    const float* xrow = xs + p * 257;
    const float s1 = xsq[n0 + p];
    float d1 = INFINITY, d2 = INFINITY;
    int i1 = 0;
    const int kbase = q * 256;
    const float* wq = w + (long)kbase * DIM;
    const float* wsq_q = wsq + kbase;

    for (int kc = 0; kc < 256; kc += 8) {
        float acc[8] = {0.f, 0.f, 0.f, 0.f, 0.f, 0.f, 0.f, 0.f};
        const float* w0 = wq + (long)kc * DIM;
#pragma unroll 2
        for (int d = 0; d < DIM; d += 4) {
            float x0 = xrow[d + 0];
            float x1 = xrow[d + 1];
            float x2 = xrow[d + 2];
            float x3 = xrow[d + 3];
#pragma unroll
            for (int j = 0; j < 8; ++j) {
                const float4 wv = *reinterpret_cast<const float4*>(w0 + j * DIM + d);
                acc[j] = __fmaf_rn(x0, wv.x, acc[j]);
                acc[j] = __fmaf_rn(x1, wv.y, acc[j]);
                acc[j] = __fmaf_rn(x2, wv.z, acc[j]);
                acc[j] = __fmaf_rn(x3, wv.w, acc[j]);
            }
        }
#pragma unroll
        for (int j = 0; j < 8; ++j) {
            // np: fl32( fl32(xsq + wsq_k) - fl32(2*dot_k) )
            float tk = __fadd_rn(s1, wsq_q[kc + j]);
            float dist = __fsub_rn(tk, __fmul_rn(2.0f, acc[j]));
            if (dist < d1) { d2 = d1; d1 = dist; i1 = kbase + kc + j; }
            else if (dist < d2) { d2 = dist; }
        }
    }

    sd1[q][p] = d1; sd2[q][p] = d2; si1[q][p] = i1;
    __syncthreads();
    if (q == 0) {
        float bd1 = sd1[0][p], bd2 = sd2[0][p];
        int bi = si1[0][p];
#pragma unroll
        for (int j = 1; j < 4; ++j) {
            float a1 = sd1[j][p], a2 = sd2[j][p];
            int ai = si1[j][p];
            if (a1 < bd1) { bd2 = fminf(bd1, a2); bd1 = a1; bi = ai; }
            else { bd2 = fminf(bd2, fminf(a1, a2)); }
        }
        const long n = n0 + p;
        idx[n] = bi;
        // flag if grid margin <= ~4 ulp(d1): tie/adjacent buckets -> exact refine
        if (__fsub_rn(bd2, bd1) <= bd1 * 4.8e-7f) {
            int pos = atomicAdd(flag_count, 1);
            if (pos < MAX_FLAGS) flags[pos] = (int)n;
        }
    }
}

// ---------- kernel 4: exact-dot refine for near-tie pixels (np rounding + first-index) ----------
__global__ __launch_bounds__(256)
void k_refine(const float* __restrict__ x, const float* __restrict__ w,
              const float* __restrict__ wsq, const float* __restrict__ xsq,
              const int* __restrict__ flags, const int* __restrict__ flag_count,
              int* __restrict__ idx) {
    __shared__ float xsf[DIM];
    __shared__ float rd[256];
    __shared__ int   ri[256];
    int nf = *flag_count;
    if (nf > MAX_FLAGS) nf = MAX_FLAGS;
    const int t = threadIdx.x;
    for (int fi = blockIdx.x; fi < nf; fi += gridDim.x) {
        int n = flags[fi];
        int b = n >> 12, hw = n & 4095;
        const float* xp = x + (long)b * DIM * HW + hw;
        __syncthreads();
        xsf[t] = xp[(long)t * HW];
        __syncthreads();
        const float s1 = xsq[n];
        float best = INFINITY;
        int bi = 1 << 30;
        for (int k = t; k < NUM_K; k += 256) {
            const float* wr = w + (long)k * DIM;
            double dot = 0.0;
            for (int d = 0; d < DIM; ++d) {
                dot = fma((double)wr[d], (double)xsf[d], dot);
            }
            float dots = (float)dot;  // correctly-rounded f32 dot (ML estimate of sgemm's)
            float dk = __fsub_rn(__fadd_rn(s1, wsq[k]), __fmul_rn(2.0f, dots));
            if (dk < best || (dk == best && k < bi)) { best = dk; bi = k; }
        }
        rd[t] = best; ri[t] = bi;
        __syncthreads();
        if (t == 0) {
            float bb = rd[0]; int bbi = ri[0];
            for (int j = 1; j < 256; ++j) {
                if (rd[j] < bb || (rd[j] == bb && ri[j] < bbi)) { bb = rd[j]; bbi = ri[j]; }
            }
            idx[n] = bbi;
        }
    }
}

// ---------- kernel 5: gather + straight-through + loss ----------
__global__ __launch_bounds__(256, 2)
void k_quant(const float* __restrict__ x, const float* __restrict__ w,
             const int* __restrict__ idx, float* __restrict__ qout,
             float* __restrict__ iout, float* __restrict__ loss) {
    __shared__ float wrow[64 * 257];
    __shared__ int lidx[64];
    __shared__ float part[4];
    const int t = threadIdx.x;
    const long n0 = (long)blockIdx.x * 64;
    const int b = (int)(n0 >> 12), hw0 = (int)(n0 & 4095);

    if (t < 64) lidx[t] = idx[n0 + t];
    __syncthreads();
    for (int i = 0; i < 64; ++i) {
        wrow[i * 257 + t] = w[(long)lidx[i] * DIM + t];
    }
    if (t < 64) iout[n0 + t] = (float)lidx[t];
    __syncthreads();

    const int p = t & 63, cg = t >> 6;
    const float* xb = x + (long)b * DIM * HW + hw0;
    float* qb = qout + (long)b * DIM * HW + hw0;
    float lsum = 0.f;
    for (int i = 0; i < 64; ++i) {
        int c = cg * 64 + i;
        float qv = wrow[p * 257 + c];
        long off = (long)c * HW + p;
        float xv = xb[off];
        float diff = __fsub_rn(qv, xv);     // q - x
        qb[off] = __fadd_rn(xv, diff);      // straight-through x + (q - x)
        lsum = __fmaf_rn(diff, diff, lsum);
    }
#pragma unroll
    for (int off = 32; off; off >>= 1) lsum += __shfl_down(lsum, off);
    if ((t & 63) == 0) part[t >> 6] = lsum;
    __syncthreads();
    if (t == 0) {
        float tot = (part[0] + part[1]) + (part[2] + part[3]);
        atomicAdd(loss, tot * (1.25f / 16777216.f));
    }
}

extern "C" void kernel_launch(void* const* d_in, const int* in_sizes, int n_in,
                              void* d_out, int out_size, void* d_ws, size_t ws_size,
                              hipStream_t stream) {
    const float* x = (const float*)d_in[0];
    const float* w = (const float*)d_in[1];

    float* qout = (float*)d_out;               // 16777216 elems
    float* iout = qout + QELEMS;               // 65536 elems (indices as float)
    float* loss = iout + NPIX;                 // 1 elem

    int*   idx        = (int*)d_ws;                                   // 65536 ints
    float* wsq        = (float*)((char*)d_ws + NPIX * sizeof(int));   // 1024 floats
    float* xsq        = wsq + NUM_K;                                  // 65536 floats
    int*   flags      = (int*)(xsq + NPIX);                           // MAX_FLAGS ints
    int*   flag_count = flags + MAX_FLAGS;                            // 1 int

    hipMemsetAsync(loss, 0, sizeof(float), stream);
    hipMemsetAsync(flag_count, 0, sizeof(int), stream);

    k_wsq<<<4, 256, 0, stream>>>(w, wsq);
    k_xsq<<<NPIX / 256, 256, 0, stream>>>(x, xsq);
    k_argmin<<<NPIX / 64, 256, 0, stream>>>(x, w, wsq, xsq, idx, flags, flag_count);
    k_refine<<<256, 256, 0, stream>>>(x, w, wsq, xsq, flags, flag_count, idx);
    k_quant<<<NPIX / 64, 256, 0, stream>>>(x, w, idx, qout, iout, loss);
}

// Round 3
// 601.810 us; speedup vs baseline: 3.6066x; 3.6066x over previous
//
#include <hip/hip_runtime.h>
#include <math.h>

#define NUM_K 1024
#define DIM 256
#define HW 4096          // 64*64
#define NPIX 65536       // 16*4096
#define QELEMS 16777216  // 16*256*4096
#define MAX_FLAGS 16384

typedef short bf16x8 __attribute__((ext_vector_type(8)));
typedef float f32x4 __attribute__((ext_vector_type(4)));

__device__ __forceinline__ unsigned short f32_to_bf16_rne(float f) {
    unsigned int u = __float_as_uint(f);
    unsigned int r = u + 0x7FFFu + ((u >> 16) & 1u);
    return (unsigned short)(r >> 16);
}
__device__ __forceinline__ float bf16_to_f32(unsigned short h) {
    return __uint_as_float(((unsigned int)h) << 16);
}

// ---------------------------------------------------------------------------
// numpy-replicated f32 sum of squares over 256 elements (pairwise SIMD tree).
// (validated bit-exact vs harness numpy in round 2)
// ---------------------------------------------------------------------------
__device__ __forceinline__ float np_sumsq_256(const float* __restrict__ p, long stride) {
    float blk0 = 0.f, blk1 = 0.f;
#pragma unroll
    for (int h = 0; h < 2; ++h) {
        const float* base = p + (long)h * 128 * stride;
        float s[16];
#pragma unroll
        for (int L = 0; L < 16; ++L) {
            float a0 = base[(long)(L)       * stride]; a0 = __fmul_rn(a0, a0);
            float a1 = base[(long)(16 + L)  * stride]; a1 = __fmul_rn(a1, a1);
            float a2 = base[(long)(32 + L)  * stride]; a2 = __fmul_rn(a2, a2);
            float a3 = base[(long)(48 + L)  * stride]; a3 = __fmul_rn(a3, a3);
            float a4 = base[(long)(64 + L)  * stride]; a4 = __fmul_rn(a4, a4);
            float a5 = base[(long)(80 + L)  * stride]; a5 = __fmul_rn(a5, a5);
            float a6 = base[(long)(96 + L)  * stride]; a6 = __fmul_rn(a6, a6);
            float a7 = base[(long)(112 + L) * stride]; a7 = __fmul_rn(a7, a7);
            float t1 = __fadd_rn(a0, a1);
            float t2 = __fadd_rn(a2, a3);
            float t3 = __fadd_rn(a4, a5);
            float t4 = __fadd_rn(a6, a7);
            s[L] = __fadd_rn(__fadd_rn(t1, t2), __fadd_rn(t3, t4));
        }
        float c0 = __fadd_rn(s[0], s[8]);
        float c1 = __fadd_rn(s[1], s[9]);
        float c2 = __fadd_rn(s[2], s[10]);
        float c3 = __fadd_rn(s[3], s[11]);
        float c4 = __fadd_rn(s[4], s[12]);
        float c5 = __fadd_rn(s[5], s[13]);
        float c6 = __fadd_rn(s[6], s[14]);
        float c7 = __fadd_rn(s[7], s[15]);
        float d0 = __fadd_rn(c0, c4);
        float d1 = __fadd_rn(c1, c5);
        float d2 = __fadd_rn(c2, c6);
        float d3 = __fadd_rn(c3, c7);
        float e0 = __fadd_rn(d0, d2);
        float e1 = __fadd_rn(d1, d3);
        float r  = __fadd_rn(e0, e1);
        if (h == 0) blk0 = r; else blk1 = r;
    }
    return __fadd_rn(blk0, blk1);
}

__global__ __launch_bounds__(256) void k_wsq(const float* __restrict__ w, float* __restrict__ wsq) {
    int k = blockIdx.x * 256 + threadIdx.x;
    if (k < NUM_K) wsq[k] = np_sumsq_256(w + (long)k * DIM, 1);
}

__global__ __launch_bounds__(256) void k_xsq(const float* __restrict__ x, float* __restrict__ xsq) {
    int n = blockIdx.x * 256 + threadIdx.x;
    int b = n >> 12, hw = n & 4095;
    xsq[n] = np_sumsq_256(x + (long)b * DIM * HW + hw, HW);
}

// ---------------------------------------------------------------------------
// w -> frag-major split-bf16: for B-frag of mfma_f32_16x16x32_bf16:
// lane fl: col(code-in-tile)=fl&15, k = 8*(fl>>4)+j. Flat layout:
// addr = ((ctile*8 + ks)*64 + fl)*8 + j ; ctile=code>>4, ks=d>>5.
// ---------------------------------------------------------------------------
__global__ __launch_bounds__(256)
void k_wfrag(const float* __restrict__ w, short* __restrict__ whi, short* __restrict__ wlo) {
    int id = blockIdx.x * 256 + threadIdx.x;   // 32768 = 1024 codes * 32 chunks
    int code = id >> 5;
    int c = id & 31;                            // d-chunk of 8: d = c*8+j
    const float* src = w + (long)code * DIM + c * 8;
    unsigned short h[8], l[8];
#pragma unroll
    for (int j = 0; j < 8; ++j) {
        float v = src[j];
        unsigned short hh = f32_to_bf16_rne(v);
        float r = __fsub_rn(v, bf16_to_f32(hh));
        h[j] = hh;
        l[j] = f32_to_bf16_rne(r);
    }
    int fl = ((c & 3) << 4) | (code & 15);
    long addr = ((((long)(code >> 4) * 8 + (c >> 2)) * 64 + fl) * 8);
    bf16x8 vh, vl;
#pragma unroll
    for (int j = 0; j < 8; ++j) { vh[j] = (short)h[j]; vl[j] = (short)l[j]; }
    *(bf16x8*)(whi + addr) = vh;
    *(bf16x8*)(wlo + addr) = vl;
}

// ---------------------------------------------------------------------------
// MFMA argmin: block = 64 pixels x 512 codes, 4 waves (each 64px x 128 codes).
// A (x tile) converted in-kernel to frag-major split-bf16 in LDS (once).
// B streamed from frag-major global (L2-resident). acc[m4][n8] f32x4.
// Epilogue: np-grid dist, per-lane (d1,d2,i1), 16-lane butterfly, partials.
// ---------------------------------------------------------------------------
#define A_SLOT(ks,m,fl) ((((ks)*4+(m))*64+(fl))*8)

__global__ __launch_bounds__(256, 2)
void k_argmin_mfma(const float* __restrict__ x,
                   const short* __restrict__ whi, const short* __restrict__ wlo,
                   const float* __restrict__ wsq, const float* __restrict__ xsq,
                   float* __restrict__ pd1, float* __restrict__ pd2, int* __restrict__ pi1) {
    __shared__ short ahi[8 * 4 * 64 * 8];   // [ks][m][fl][j] 32KB
    __shared__ short alo[8 * 4 * 64 * 8];   // 32KB

    const int t = threadIdx.x;
    const int lane = t & 63;
    const int q = t >> 6;                    // wave id
    const int tile = blockIdx.x >> 1;        // 1024 pixel tiles of 64
    const int slice = blockIdx.x & 1;        // code slice of 512

    const int b = tile >> 6;                 // 64 tiles per image
    const int hw0 = (tile & 63) * 64;
    const float* xb = x + (long)b * (DIM * HW) + hw0 + lane;  // + d*HW

    // ---- stage A: convert 64px x 256d to frag-major split-bf16 LDS ----
    // thread: px = lane, chunks c = q*8 + i (8 consecutive d each)
#pragma unroll
    for (int i = 0; i < 8; ++i) {
        int c = q * 8 + i;
        float v[8];
#pragma unroll
        for (int jj = 0; jj < 8; ++jj) v[jj] = xb[(long)(c * 8 + jj) * HW];
        bf16x8 vh, vl;
#pragma unroll
        for (int jj = 0; jj < 8; ++jj) {
            unsigned short hh = f32_to_bf16_rne(v[jj]);
            float r = __fsub_rn(v[jj], bf16_to_f32(hh));
            vh[jj] = (short)hh;
            vl[jj] = (short)f32_to_bf16_rne(r);
        }
        int slot = A_SLOT(c >> 2, lane >> 4, ((c & 3) << 4) | (lane & 15));
        *(bf16x8*)(ahi + slot) = vh;
        *(bf16x8*)(alo + slot) = vl;
    }
    __syncthreads();

    // ---- main GEMM: 8 ksteps (K=32 each) x 8 ntiles x 4 mtiles x 3 products ----
    const int ct0 = slice * 32 + q * 8;      // 16-code tile base
    f32x4 acc[4][8];
#pragma unroll
    for (int m = 0; m < 4; ++m)
#pragma unroll
        for (int n = 0; n < 8; ++n) acc[m][n] = (f32x4){0.f, 0.f, 0.f, 0.f};

    for (int ks = 0; ks < 8; ++ks) {
        bf16x8 ah[4], al[4];
#pragma unroll
        for (int m = 0; m < 4; ++m) {
            ah[m] = *(const bf16x8*)(ahi + A_SLOT(ks, m, lane));
            al[m] = *(const bf16x8*)(alo + A_SLOT(ks, m, lane));
        }
#pragma unroll
        for (int n = 0; n < 8; ++n) {
            long baddr = (((long)(ct0 + n) * 8 + ks) * 64 + lane) * 8;
            bf16x8 bh = *(const bf16x8*)(whi + baddr);
            bf16x8 bl = *(const bf16x8*)(wlo + baddr);
#pragma unroll
            for (int m = 0; m < 4; ++m) {
                acc[m][n] = __builtin_amdgcn_mfma_f32_16x16x32_bf16(ah[m], bh, acc[m][n], 0, 0, 0);
                acc[m][n] = __builtin_amdgcn_mfma_f32_16x16x32_bf16(al[m], bh, acc[m][n], 0, 0, 0);
                acc[m][n] = __builtin_amdgcn_mfma_f32_16x16x32_bf16(ah[m], bl, acc[m][n], 0, 0, 0);
            }
        }
    }

    // ---- epilogue: dist = fl(fl(s1+wsq) - 2*dot); track d1,d2,i1 ----
    const long px0 = (long)tile * 64;
    const int rbase = (lane >> 4) * 4;       // row within 16-tile
    float s1v[4][4];
#pragma unroll
    for (int m = 0; m < 4; ++m)
#pragma unroll
        for (int r = 0; r < 4; ++r) s1v[m][r] = xsq[px0 + 16 * m + rbase + r];

    float bd1[4][4], bd2[4][4];
    int bi1[4][4];
#pragma unroll
    for (int m = 0; m < 4; ++m)
#pragma unroll
        for (int r = 0; r < 4; ++r) { bd1[m][r] = INFINITY; bd2[m][r] = INFINITY; bi1[m][r] = 0; }

#pragma unroll
    for (int n = 0; n < 8; ++n) {
        int code = (ct0 + n) * 16 + (lane & 15);
        float wq = wsq[code];
#pragma unroll
        for (int m = 0; m < 4; ++m) {
#pragma unroll
            for (int r = 0; r < 4; ++r) {
                float tt = __fadd_rn(s1v[m][r], wq);
                float dist = __fmaf_rn(-2.0f, acc[m][n][r], tt);
                bool c1 = dist < bd1[m][r];
                bool c2 = dist < bd2[m][r];
                bd2[m][r] = c1 ? bd1[m][r] : (c2 ? dist : bd2[m][r]);
                bd1[m][r] = c1 ? dist : bd1[m][r];
                bi1[m][r] = c1 ? code : bi1[m][r];
            }
        }
    }

    // butterfly across the 16 lanes (lane&15) holding different codes
#pragma unroll
    for (int step = 1; step < 16; step <<= 1) {
#pragma unroll
        for (int m = 0; m < 4; ++m) {
#pragma unroll
            for (int r = 0; r < 4; ++r) {
                float od1 = __shfl_xor(bd1[m][r], step);
                float od2 = __shfl_xor(bd2[m][r], step);
                int   oi  = __shfl_xor(bi1[m][r], step);
                bool take = (od1 < bd1[m][r]) || ((od1 == bd1[m][r]) && (oi < bi1[m][r]));
                float nd2 = fminf(fmaxf(od1, bd1[m][r]), fminf(od2, bd2[m][r]));
                bd1[m][r] = take ? od1 : bd1[m][r];
                bi1[m][r] = take ? oi : bi1[m][r];
                bd2[m][r] = nd2;
            }
        }
    }

    if ((lane & 15) == 0) {
        const long ws_id = slice * 4 + q;    // ascending code order
#pragma unroll
        for (int m = 0; m < 4; ++m) {
#pragma unroll
            for (int r = 0; r < 4; ++r) {
                long pix = px0 + 16 * m + rbase + r;
                pd1[ws_id * NPIX + pix] = bd1[m][r];
                pd2[ws_id * NPIX + pix] = bd2[m][r];
                pi1[ws_id * NPIX + pix] = bi1[m][r];
            }
        }
    }
}

// ---------- combine 8 code-slice partials, flag near-ties ----------
__global__ __launch_bounds__(256)
void k_combine(const float* __restrict__ pd1, const float* __restrict__ pd2,
               const int* __restrict__ pi1, int* __restrict__ idx,
               int* __restrict__ flags, int* __restrict__ flag_count) {
    int n = blockIdx.x * 256 + threadIdx.x;
    float d1 = pd1[n], d2 = pd2[n];
    int i1 = pi1[n];
#pragma unroll
    for (int s = 1; s < 8; ++s) {
        float a1 = pd1[(long)s * NPIX + n];
        float a2 = pd2[(long)s * NPIX + n];
        int   ai = pi1[(long)s * NPIX + n];
        bool take = (a1 < d1) || ((a1 == d1) && (ai < i1));
        float nd2 = fminf(fmaxf(a1, d1), fminf(a2, d2));
        d1 = take ? a1 : d1;
        i1 = take ? ai : i1;
        d2 = nd2;
    }
    idx[n] = i1;
    if (__fsub_rn(d2, d1) <= d1 * 6.0e-7f) {
        int pos = atomicAdd(flag_count, 1);
        if (pos < MAX_FLAGS) flags[pos] = n;
    }
}

// ---------- fallback VALU argmin (round-2 proven path) ----------
__global__ __launch_bounds__(256, 2)
void k_argmin_valu(const float* __restrict__ x, const float* __restrict__ w,
                   const float* __restrict__ wsq, const float* __restrict__ xsq,
                   int* __restrict__ idx, int* __restrict__ flags, int* __restrict__ flag_count) {
    __shared__ float xs[64 * 257];
    __shared__ float sd1[4][64];
    __shared__ float sd2[4][64];
    __shared__ int   si1[4][64];

    const int t = threadIdx.x;
    const int p = t & 63;
    const int q = t >> 6;
    const long n0 = (long)blockIdx.x * 64;
    const int b = (int)(n0 >> 12);
    const int hw0 = (int)(n0 & 4095);
    const float* xb = x + (long)b * DIM * HW + hw0;

    for (int i = 0; i < 64; ++i) {
        int c = q * 64 + i;
        xs[p * 257 + c] = xb[(long)c * HW + p];
    }
    __syncthreads();

    const float* xrow = xs + p * 257;
    const float s1 = xsq[n0 + p];
    float d1 = INFINITY, d2 = INFINITY;
    int i1 = 0;
    const int kbase = q * 256;
    const float* wq = w + (long)kbase * DIM;
    const float* wsq_q = wsq + kbase;

    for (int kc = 0; kc < 256; kc += 8) {
        float acc[8] = {0.f, 0.f, 0.f, 0.f, 0.f, 0.f, 0.f, 0.f};
        const float* w0 = wq + (long)kc * DIM;
#pragma unroll 2
        for (int d = 0; d < DIM; d += 4) {
            float x0 = xrow[d + 0];
            float x1 = xrow[d + 1];
            float x2 = xrow[d + 2];
            float x3 = xrow[d + 3];
#pragma unroll
            for (int j = 0; j < 8; ++j) {
                const float4 wv = *reinterpret_cast<const float4*>(w0 + j * DIM + d);
                acc[j] = __fmaf_rn(x0, wv.x, acc[j]);
                acc[j] = __fmaf_rn(x1, wv.y, acc[j]);
                acc[j] = __fmaf_rn(x2, wv.z, acc[j]);
                acc[j] = __fmaf_rn(x3, wv.w, acc[j]);
            }
        }
#pragma unroll
        for (int j = 0; j < 8; ++j) {
            float tk = __fadd_rn(s1, wsq_q[kc + j]);
            float dist = __fsub_rn(tk, __fmul_rn(2.0f, acc[j]));
            if (dist < d1) { d2 = d1; d1 = dist; i1 = kbase + kc + j; }
            else if (dist < d2) { d2 = dist; }
        }
    }

    sd1[q][p] = d1; sd2[q][p] = d2; si1[q][p] = i1;
    __syncthreads();
    if (q == 0) {
        float bd1 = sd1[0][p], bd2 = sd2[0][p];
        int bi = si1[0][p];
#pragma unroll
        for (int j = 1; j < 4; ++j) {
            float a1 = sd1[j][p], a2 = sd2[j][p];
            int ai = si1[j][p];
            if (a1 < bd1) { bd2 = fminf(bd1, a2); bd1 = a1; bi = ai; }
            else { bd2 = fminf(bd2, fminf(a1, a2)); }
        }
        const long n = n0 + p;
        idx[n] = bi;
        if (__fsub_rn(bd2, bd1) <= bd1 * 6.0e-7f) {
            int pos = atomicAdd(flag_count, 1);
            if (pos < MAX_FLAGS) flags[pos] = (int)n;
        }
    }
}

// ---------- exact-dot refine for near-tie pixels (np rounding + first-index) ----------
__global__ __launch_bounds__(256)
void k_refine(const float* __restrict__ x, const float* __restrict__ w,
              const float* __restrict__ wsq, const float* __restrict__ xsq,
              const int* __restrict__ flags, const int* __restrict__ flag_count,
              int* __restrict__ idx) {
    __shared__ float xsf[DIM];
    __shared__ float rd[256];
    __shared__ int   ri[256];
    int nf = *flag_count;
    if (nf > MAX_FLAGS) nf = MAX_FLAGS;
    const int t = threadIdx.x;
    for (int fi = blockIdx.x; fi < nf; fi += gridDim.x) {
        int n = flags[fi];
        int b = n >> 12, hw = n & 4095;
        const float* xp = x + (long)b * DIM * HW + hw;
        __syncthreads();
        xsf[t] = xp[(long)t * HW];
        __syncthreads();
        const float s1 = xsq[n];
        float best = INFINITY;
        int bi = 1 << 30;
        for (int k = t; k < NUM_K; k += 256) {
            const float* wr = w + (long)k * DIM;
            double dot = 0.0;
            for (int d = 0; d < DIM; ++d) {
                dot = fma((double)wr[d], (double)xsf[d], dot);
            }
            float dots = (float)dot;
            float dk = __fsub_rn(__fadd_rn(s1, wsq[k]), __fmul_rn(2.0f, dots));
            if (dk < best || (dk == best && k < bi)) { best = dk; bi = k; }
        }
        rd[t] = best; ri[t] = bi;
        __syncthreads();
        if (t == 0) {
            float bb = rd[0]; int bbi = ri[0];
            for (int j = 1; j < 256; ++j) {
                if (rd[j] < bb || (rd[j] == bb && ri[j] < bbi)) { bb = rd[j]; bbi = ri[j]; }
            }
            idx[n] = bbi;
        }
    }
}

// ---------- gather + straight-through + loss ----------
__global__ __launch_bounds__(256, 2)
void k_quant(const float* __restrict__ x, const float* __restrict__ w,
             const int* __restrict__ idx, float* __restrict__ qout,
             float* __restrict__ iout, float* __restrict__ loss) {
    __shared__ float wrow[64 * 257];
    __shared__ int lidx[64];
    __shared__ float part[4];
    const int t = threadIdx.x;
    const long n0 = (long)blockIdx.x * 64;
    const int b = (int)(n0 >> 12), hw0 = (int)(n0 & 4095);

    if (t < 64) lidx[t] = idx[n0 + t];
    __syncthreads();
    for (int i = 0; i < 64; ++i) {
        wrow[i * 257 + t] = w[(long)lidx[i] * DIM + t];
    }
    if (t < 64) iout[n0 + t] = (float)lidx[t];
    __syncthreads();

    const int p = t & 63, cg = t >> 6;
    const float* xb = x + (long)b * DIM * HW + hw0;
    float* qb = qout + (long)b * DIM * HW + hw0;
    float lsum = 0.f;
    for (int i = 0; i < 64; ++i) {
        int c = cg * 64 + i;
        float qv = wrow[p * 257 + c];
        long off = (long)c * HW + p;
        float xv = xb[off];
        float diff = __fsub_rn(qv, xv);
        qb[off] = __fadd_rn(xv, diff);
        lsum = __fmaf_rn(diff, diff, lsum);
    }
#pragma unroll
    for (int off = 32; off; off >>= 1) lsum += __shfl_down(lsum, off);
    if ((t & 63) == 0) part[t >> 6] = lsum;
    __syncthreads();
    if (t == 0) {
        float tot = (part[0] + part[1]) + (part[2] + part[3]);
        atomicAdd(loss, tot * (1.25f / 16777216.f));
    }
}

extern "C" void kernel_launch(void* const* d_in, const int* in_sizes, int n_in,
                              void* d_out, int out_size, void* d_ws, size_t ws_size,
                              hipStream_t stream) {
    const float* x = (const float*)d_in[0];
    const float* w = (const float*)d_in[1];

    float* qout = (float*)d_out;
    float* iout = qout + QELEMS;
    float* loss = iout + NPIX;

    char* wp = (char*)d_ws;
    int*   idx        = (int*)wp;                 wp += (size_t)NPIX * 4;       // 256KB
    float* wsq        = (float*)wp;               wp += (size_t)NUM_K * 4;      // 4KB
    float* xsq        = (float*)wp;               wp += (size_t)NPIX * 4;       // 256KB
    int*   flags      = (int*)wp;                 wp += (size_t)MAX_FLAGS * 4;  // 64KB
    int*   flag_count = (int*)wp;                 wp += 256;
    short* whi        = (short*)wp;               wp += (size_t)NUM_K * DIM * 2; // 512KB
    short* wlo        = (short*)wp;               wp += (size_t)NUM_K * DIM * 2; // 512KB
    float* pd1        = (float*)wp;               wp += (size_t)8 * NPIX * 4;   // 2MB
    float* pd2        = (float*)wp;               wp += (size_t)8 * NPIX * 4;   // 2MB
    int*   pi1        = (int*)wp;                 wp += (size_t)8 * NPIX * 4;   // 2MB
    size_t need = (size_t)(wp - (char*)d_ws);

    hipMemsetAsync(loss, 0, sizeof(float), stream);
    hipMemsetAsync(flag_count, 0, sizeof(int), stream);

    k_wsq<<<4, 256, 0, stream>>>(w, wsq);
    k_xsq<<<NPIX / 256, 256, 0, stream>>>(x, xsq);

    if (ws_size >= need) {
        k_wfrag<<<128, 256, 0, stream>>>(w, whi, wlo);
        k_argmin_mfma<<<2048, 256, 0, stream>>>(x, whi, wlo, wsq, xsq, pd1, pd2, pi1);
        k_combine<<<NPIX / 256, 256, 0, stream>>>(pd1, pd2, pi1, idx, flags, flag_count);
    } else {
        k_argmin_valu<<<NPIX / 64, 256, 0, stream>>>(x, w, wsq, xsq, idx, flags, flag_count);
    }
    k_refine<<<256, 256, 0, stream>>>(x, w, wsq, xsq, flags, flag_count, idx);
    k_quant<<<NPIX / 64, 256, 0, stream>>>(x, w, idx, qout, iout, loss);
}

// Round 4
// 317.172 us; speedup vs baseline: 6.8433x; 1.8974x over previous
//
#include <hip/hip_runtime.h>
#include <math.h>

#define NUM_K 1024
#define DIM 256
#define HW 4096          // 64*64
#define NPIX 65536       // 16*4096
#define QELEMS 16777216  // 16*256*4096
#define MAX_FLAGS 16384

typedef short bf16x8 __attribute__((ext_vector_type(8)));
typedef float f32x4 __attribute__((ext_vector_type(4)));

__device__ __forceinline__ unsigned short f32_to_bf16_rne(float f) {
    unsigned int u = __float_as_uint(f);
    unsigned int r = u + 0x7FFFu + ((u >> 16) & 1u);
    return (unsigned short)(r >> 16);
}
__device__ __forceinline__ float bf16_to_f32(unsigned short h) {
    return __uint_as_float(((unsigned int)h) << 16);
}

// ---------------------------------------------------------------------------
// numpy-replicated f32 sum of squares over 256 elements (pairwise SIMD tree).
// (validated bit-exact vs harness numpy in rounds 2-3)
// ---------------------------------------------------------------------------
__device__ __forceinline__ float np_sumsq_256(const float* __restrict__ p, long stride) {
    float blk0 = 0.f, blk1 = 0.f;
#pragma unroll
    for (int h = 0; h < 2; ++h) {
        const float* base = p + (long)h * 128 * stride;
        float s[16];
#pragma unroll
        for (int L = 0; L < 16; ++L) {
            float a0 = base[(long)(L)       * stride]; a0 = __fmul_rn(a0, a0);
            float a1 = base[(long)(16 + L)  * stride]; a1 = __fmul_rn(a1, a1);
            float a2 = base[(long)(32 + L)  * stride]; a2 = __fmul_rn(a2, a2);
            float a3 = base[(long)(48 + L)  * stride]; a3 = __fmul_rn(a3, a3);
            float a4 = base[(long)(64 + L)  * stride]; a4 = __fmul_rn(a4, a4);
            float a5 = base[(long)(80 + L)  * stride]; a5 = __fmul_rn(a5, a5);
            float a6 = base[(long)(96 + L)  * stride]; a6 = __fmul_rn(a6, a6);
            float a7 = base[(long)(112 + L) * stride]; a7 = __fmul_rn(a7, a7);
            float t1 = __fadd_rn(a0, a1);
            float t2 = __fadd_rn(a2, a3);
            float t3 = __fadd_rn(a4, a5);
            float t4 = __fadd_rn(a6, a7);
            s[L] = __fadd_rn(__fadd_rn(t1, t2), __fadd_rn(t3, t4));
        }
        float c0 = __fadd_rn(s[0], s[8]);
        float c1 = __fadd_rn(s[1], s[9]);
        float c2 = __fadd_rn(s[2], s[10]);
        float c3 = __fadd_rn(s[3], s[11]);
        float c4 = __fadd_rn(s[4], s[12]);
        float c5 = __fadd_rn(s[5], s[13]);
        float c6 = __fadd_rn(s[6], s[14]);
        float c7 = __fadd_rn(s[7], s[15]);
        float d0 = __fadd_rn(c0, c4);
        float d1 = __fadd_rn(c1, c5);
        float d2 = __fadd_rn(c2, c6);
        float d3 = __fadd_rn(c3, c7);
        float e0 = __fadd_rn(d0, d2);
        float e1 = __fadd_rn(d1, d3);
        float r  = __fadd_rn(e0, e1);
        if (h == 0) blk0 = r; else blk1 = r;
    }
    return __fadd_rn(blk0, blk1);
}

__global__ __launch_bounds__(256) void k_wsq(const float* __restrict__ w, float* __restrict__ wsq) {
    int k = blockIdx.x * 256 + threadIdx.x;
    if (k < NUM_K) wsq[k] = np_sumsq_256(w + (long)k * DIM, 1);
}

__global__ __launch_bounds__(256) void k_xsq(const float* __restrict__ x, float* __restrict__ xsq) {
    int n = blockIdx.x * 256 + threadIdx.x;
    int b = n >> 12, hw = n & 4095;
    xsq[n] = np_sumsq_256(x + (long)b * DIM * HW + hw, HW);
}

// ---------- w transpose: wtr[d][k] = w[k][d], for coalesced refine loads ----------
__global__ __launch_bounds__(1024)
void k_wtrans(const float* __restrict__ w, float* __restrict__ wtr) {
    int d = blockIdx.x;
    int k = threadIdx.x;
    wtr[(long)d * NUM_K + k] = w[(long)k * DIM + d];
}

// ---------------------------------------------------------------------------
// w -> frag-major split-bf16 for B-frag of mfma_f32_16x16x32_bf16.
// ---------------------------------------------------------------------------
__global__ __launch_bounds__(256)
void k_wfrag(const float* __restrict__ w, short* __restrict__ whi, short* __restrict__ wlo) {
    int id = blockIdx.x * 256 + threadIdx.x;   // 32768 = 1024 codes * 32 chunks
    int code = id >> 5;
    int c = id & 31;                            // d-chunk of 8: d = c*8+j
    const float* src = w + (long)code * DIM + c * 8;
    unsigned short h[8], l[8];
#pragma unroll
    for (int j = 0; j < 8; ++j) {
        float v = src[j];
        unsigned short hh = f32_to_bf16_rne(v);
        float r = __fsub_rn(v, bf16_to_f32(hh));
        h[j] = hh;
        l[j] = f32_to_bf16_rne(r);
    }
    int fl = ((c & 3) << 4) | (code & 15);
    long addr = ((((long)(code >> 4) * 8 + (c >> 2)) * 64 + fl) * 8);
    bf16x8 vh, vl;
#pragma unroll
    for (int j = 0; j < 8; ++j) { vh[j] = (short)h[j]; vl[j] = (short)l[j]; }
    *(bf16x8*)(whi + addr) = vh;
    *(bf16x8*)(wlo + addr) = vl;
}

// ---------------------------------------------------------------------------
// MFMA argmin: block = 64 pixels x 512 codes, 4 waves (each 64px x 128 codes).
// (unchanged from round 3 — proven)
// ---------------------------------------------------------------------------
#define A_SLOT(ks,m,fl) ((((ks)*4+(m))*64+(fl))*8)

__global__ __launch_bounds__(256, 2)
void k_argmin_mfma(const float* __restrict__ x,
                   const short* __restrict__ whi, const short* __restrict__ wlo,
                   const float* __restrict__ wsq, const float* __restrict__ xsq,
                   float* __restrict__ pd1, float* __restrict__ pd2, int* __restrict__ pi1) {
    __shared__ short ahi[8 * 4 * 64 * 8];   // 32KB
    __shared__ short alo[8 * 4 * 64 * 8];   // 32KB

    const int t = threadIdx.x;
    const int lane = t & 63;
    const int q = t >> 6;
    const int tile = blockIdx.x >> 1;
    const int slice = blockIdx.x & 1;

    const int b = tile >> 6;
    const int hw0 = (tile & 63) * 64;
    const float* xb = x + (long)b * (DIM * HW) + hw0 + lane;

#pragma unroll
    for (int i = 0; i < 8; ++i) {
        int c = q * 8 + i;
        float v[8];
#pragma unroll
        for (int jj = 0; jj < 8; ++jj) v[jj] = xb[(long)(c * 8 + jj) * HW];
        bf16x8 vh, vl;
#pragma unroll
        for (int jj = 0; jj < 8; ++jj) {
            unsigned short hh = f32_to_bf16_rne(v[jj]);
            float r = __fsub_rn(v[jj], bf16_to_f32(hh));
            vh[jj] = (short)hh;
            vl[jj] = (short)f32_to_bf16_rne(r);
        }
        int slot = A_SLOT(c >> 2, lane >> 4, ((c & 3) << 4) | (lane & 15));
        *(bf16x8*)(ahi + slot) = vh;
        *(bf16x8*)(alo + slot) = vl;
    }
    __syncthreads();

    const int ct0 = slice * 32 + q * 8;
    f32x4 acc[4][8];
#pragma unroll
    for (int m = 0; m < 4; ++m)
#pragma unroll
        for (int n = 0; n < 8; ++n) acc[m][n] = (f32x4){0.f, 0.f, 0.f, 0.f};

    for (int ks = 0; ks < 8; ++ks) {
        bf16x8 ah[4], al[4];
#pragma unroll
        for (int m = 0; m < 4; ++m) {
            ah[m] = *(const bf16x8*)(ahi + A_SLOT(ks, m, lane));
            al[m] = *(const bf16x8*)(alo + A_SLOT(ks, m, lane));
        }
#pragma unroll
        for (int n = 0; n < 8; ++n) {
            long baddr = (((long)(ct0 + n) * 8 + ks) * 64 + lane) * 8;
            bf16x8 bh = *(const bf16x8*)(whi + baddr);
            bf16x8 bl = *(const bf16x8*)(wlo + baddr);
#pragma unroll
            for (int m = 0; m < 4; ++m) {
                acc[m][n] = __builtin_amdgcn_mfma_f32_16x16x32_bf16(ah[m], bh, acc[m][n], 0, 0, 0);
                acc[m][n] = __builtin_amdgcn_mfma_f32_16x16x32_bf16(al[m], bh, acc[m][n], 0, 0, 0);
                acc[m][n] = __builtin_amdgcn_mfma_f32_16x16x32_bf16(ah[m], bl, acc[m][n], 0, 0, 0);
            }
        }
    }

    const long px0 = (long)tile * 64;
    const int rbase = (lane >> 4) * 4;
    float s1v[4][4];
#pragma unroll
    for (int m = 0; m < 4; ++m)
#pragma unroll
        for (int r = 0; r < 4; ++r) s1v[m][r] = xsq[px0 + 16 * m + rbase + r];

    float bd1[4][4], bd2[4][4];
    int bi1[4][4];
#pragma unroll
    for (int m = 0; m < 4; ++m)
#pragma unroll
        for (int r = 0; r < 4; ++r) { bd1[m][r] = INFINITY; bd2[m][r] = INFINITY; bi1[m][r] = 0; }

#pragma unroll
    for (int n = 0; n < 8; ++n) {
        int code = (ct0 + n) * 16 + (lane & 15);
        float wq = wsq[code];
#pragma unroll
        for (int m = 0; m < 4; ++m) {
#pragma unroll
            for (int r = 0; r < 4; ++r) {
                float tt = __fadd_rn(s1v[m][r], wq);
                float dist = __fmaf_rn(-2.0f, acc[m][n][r], tt);
                bool c1 = dist < bd1[m][r];
                bool c2 = dist < bd2[m][r];
                bd2[m][r] = c1 ? bd1[m][r] : (c2 ? dist : bd2[m][r]);
                bd1[m][r] = c1 ? dist : bd1[m][r];
                bi1[m][r] = c1 ? code : bi1[m][r];
            }
        }
    }

#pragma unroll
    for (int step = 1; step < 16; step <<= 1) {
#pragma unroll
        for (int m = 0; m < 4; ++m) {
#pragma unroll
            for (int r = 0; r < 4; ++r) {
                float od1 = __shfl_xor(bd1[m][r], step);
                float od2 = __shfl_xor(bd2[m][r], step);
                int   oi  = __shfl_xor(bi1[m][r], step);
                bool take = (od1 < bd1[m][r]) || ((od1 == bd1[m][r]) && (oi < bi1[m][r]));
                float nd2 = fminf(fmaxf(od1, bd1[m][r]), fminf(od2, bd2[m][r]));
                bd1[m][r] = take ? od1 : bd1[m][r];
                bi1[m][r] = take ? oi : bi1[m][r];
                bd2[m][r] = nd2;
            }
        }
    }

    if ((lane & 15) == 0) {
        const long ws_id = slice * 4 + q;
#pragma unroll
        for (int m = 0; m < 4; ++m) {
#pragma unroll
            for (int r = 0; r < 4; ++r) {
                long pix = px0 + 16 * m + rbase + r;
                pd1[ws_id * NPIX + pix] = bd1[m][r];
                pd2[ws_id * NPIX + pix] = bd2[m][r];
                pi1[ws_id * NPIX + pix] = bi1[m][r];
            }
        }
    }
}

// ---------- combine 8 code-slice partials, flag near-ties ----------
__global__ __launch_bounds__(256)
void k_combine(const float* __restrict__ pd1, const float* __restrict__ pd2,
               const int* __restrict__ pi1, int* __restrict__ idx,
               int* __restrict__ flags, int* __restrict__ flag_count) {
    int n = blockIdx.x * 256 + threadIdx.x;
    float d1 = pd1[n], d2 = pd2[n];
    int i1 = pi1[n];
#pragma unroll
    for (int s = 1; s < 8; ++s) {
        float a1 = pd1[(long)s * NPIX + n];
        float a2 = pd2[(long)s * NPIX + n];
        int   ai = pi1[(long)s * NPIX + n];
        bool take = (a1 < d1) || ((a1 == d1) && (ai < i1));
        float nd2 = fminf(fmaxf(a1, d1), fminf(a2, d2));
        d1 = take ? a1 : d1;
        i1 = take ? ai : i1;
        d2 = nd2;
    }
    idx[n] = i1;
    if (__fsub_rn(d2, d1) <= d1 * 6.0e-7f) {
        int pos = atomicAdd(flag_count, 1);
        if (pos < MAX_FLAGS) flags[pos] = n;
    }
}

// ---------- fallback VALU argmin (round-2 proven path) ----------
__global__ __launch_bounds__(256, 2)
void k_argmin_valu(const float* __restrict__ x, const float* __restrict__ w,
                   const float* __restrict__ wsq, const float* __restrict__ xsq,
                   int* __restrict__ idx, int* __restrict__ flags, int* __restrict__ flag_count) {
    __shared__ float xs[64 * 257];
    __shared__ float sd1[4][64];
    __shared__ float sd2[4][64];
    __shared__ int   si1[4][64];

    const int t = threadIdx.x;
    const int p = t & 63;
    const int q = t >> 6;
    const long n0 = (long)blockIdx.x * 64;
    const int b = (int)(n0 >> 12);
    const int hw0 = (int)(n0 & 4095);
    const float* xb = x + (long)b * DIM * HW + hw0;

    for (int i = 0; i < 64; ++i) {
        int c = q * 64 + i;
        xs[p * 257 + c] = xb[(long)c * HW + p];
    }
    __syncthreads();

    const float* xrow = xs + p * 257;
    const float s1 = xsq[n0 + p];
    float d1 = INFINITY, d2 = INFINITY;
    int i1 = 0;
    const int kbase = q * 256;
    const float* wq = w + (long)kbase * DIM;
    const float* wsq_q = wsq + kbase;

    for (int kc = 0; kc < 256; kc += 8) {
        float acc[8] = {0.f, 0.f, 0.f, 0.f, 0.f, 0.f, 0.f, 0.f};
        const float* w0 = wq + (long)kc * DIM;
#pragma unroll 2
        for (int d = 0; d < DIM; d += 4) {
            float x0 = xrow[d + 0];
            float x1 = xrow[d + 1];
            float x2 = xrow[d + 2];
            float x3 = xrow[d + 3];
#pragma unroll
            for (int j = 0; j < 8; ++j) {
                const float4 wv = *reinterpret_cast<const float4*>(w0 + j * DIM + d);
                acc[j] = __fmaf_rn(x0, wv.x, acc[j]);
                acc[j] = __fmaf_rn(x1, wv.y, acc[j]);
                acc[j] = __fmaf_rn(x2, wv.z, acc[j]);
                acc[j] = __fmaf_rn(x3, wv.w, acc[j]);
            }
        }
#pragma unroll
        for (int j = 0; j < 8; ++j) {
            float tk = __fadd_rn(s1, wsq_q[kc + j]);
            float dist = __fsub_rn(tk, __fmul_rn(2.0f, acc[j]));
            if (dist < d1) { d2 = d1; d1 = dist; i1 = kbase + kc + j; }
            else if (dist < d2) { d2 = dist; }
        }
    }

    sd1[q][p] = d1; sd2[q][p] = d2; si1[q][p] = i1;
    __syncthreads();
    if (q == 0) {
        float bd1 = sd1[0][p], bd2 = sd2[0][p];
        int bi = si1[0][p];
#pragma unroll
        for (int j = 1; j < 4; ++j) {
            float a1 = sd1[j][p], a2 = sd2[j][p];
            int ai = si1[j][p];
            if (a1 < bd1) { bd2 = fminf(bd1, a2); bd1 = a1; bi = ai; }
            else { bd2 = fminf(bd2, fminf(a1, a2)); }
        }
        const long n = n0 + p;
        idx[n] = bi;
        if (__fsub_rn(bd2, bd1) <= bd1 * 6.0e-7f) {
            int pos = atomicAdd(flag_count, 1);
            if (pos < MAX_FLAGS) flags[pos] = (int)n;
        }
    }
}

// ---------------------------------------------------------------------------
// exact-dot refine v2: one block per flagged pixel, 1024 threads = 1 code each.
// Coalesced wT[d][k] loads, 4 independent f64 accumulators, LDS lexicographic
// (dist, index) tree-reduce -> same first-index semantics as rounds 2-3.
// ---------------------------------------------------------------------------
__global__ __launch_bounds__(1024)
void k_refine(const float* __restrict__ x, const float* __restrict__ wtr,
              const float* __restrict__ wsq, const float* __restrict__ xsq,
              const int* __restrict__ flags, const int* __restrict__ flag_count,
              int* __restrict__ idx) {
    __shared__ float xsf[DIM];
    __shared__ float rd[1024];
    __shared__ int   ri[1024];
    int nf = *flag_count;
    if (nf > MAX_FLAGS) nf = MAX_FLAGS;
    const int t = threadIdx.x;
    for (int fi = blockIdx.x; fi < nf; fi += gridDim.x) {
        int n = flags[fi];
        int b = n >> 12, hw = n & 4095;
        const float* xp = x + (long)b * DIM * HW + hw;
        __syncthreads();
        if (t < DIM) xsf[t] = xp[(long)t * HW];
        __syncthreads();
        const float s1 = xsq[n];
        double a0 = 0.0, a1 = 0.0, a2 = 0.0, a3 = 0.0;
#pragma unroll 8
        for (int d = 0; d < DIM; d += 4) {
            a0 = fma((double)wtr[(long)(d + 0) * NUM_K + t], (double)xsf[d + 0], a0);
            a1 = fma((double)wtr[(long)(d + 1) * NUM_K + t], (double)xsf[d + 1], a1);
            a2 = fma((double)wtr[(long)(d + 2) * NUM_K + t], (double)xsf[d + 2], a2);
            a3 = fma((double)wtr[(long)(d + 3) * NUM_K + t], (double)xsf[d + 3], a3);
        }
        float dots = (float)((a0 + a1) + (a2 + a3));
        float dk = __fsub_rn(__fadd_rn(s1, wsq[t]), __fmul_rn(2.0f, dots));
        rd[t] = dk; ri[t] = t;
        __syncthreads();
        for (int s = 512; s > 0; s >>= 1) {
            if (t < s) {
                float ra = rd[t + s]; int ia = ri[t + s];
                if (ra < rd[t] || (ra == rd[t] && ia < ri[t])) { rd[t] = ra; ri[t] = ia; }
            }
            __syncthreads();
        }
        if (t == 0) idx[n] = ri[0];
    }
}

// ---------- gather + straight-through + loss ----------
__global__ __launch_bounds__(256, 2)
void k_quant(const float* __restrict__ x, const float* __restrict__ w,
             const int* __restrict__ idx, float* __restrict__ qout,
             float* __restrict__ iout, float* __restrict__ loss) {
    __shared__ float wrow[64 * 257];
    __shared__ int lidx[64];
    __shared__ float part[4];
    const int t = threadIdx.x;
    const long n0 = (long)blockIdx.x * 64;
    const int b = (int)(n0 >> 12), hw0 = (int)(n0 & 4095);

    if (t < 64) lidx[t] = idx[n0 + t];
    __syncthreads();
    for (int i = 0; i < 64; ++i) {
        wrow[i * 257 + t] = w[(long)lidx[i] * DIM + t];
    }
    if (t < 64) iout[n0 + t] = (float)lidx[t];
    __syncthreads();

    const int p = t & 63, cg = t >> 6;
    const float* xb = x + (long)b * DIM * HW + hw0;
    float* qb = qout + (long)b * DIM * HW + hw0;
    float lsum = 0.f;
    for (int i = 0; i < 64; ++i) {
        int c = cg * 64 + i;
        float qv = wrow[p * 257 + c];
        long off = (long)c * HW + p;
        float xv = xb[off];
        float diff = __fsub_rn(qv, xv);
        qb[off] = __fadd_rn(xv, diff);
        lsum = __fmaf_rn(diff, diff, lsum);
    }
#pragma unroll
    for (int off = 32; off; off >>= 1) lsum += __shfl_down(lsum, off);
    if ((t & 63) == 0) part[t >> 6] = lsum;
    __syncthreads();
    if (t == 0) {
        float tot = (part[0] + part[1]) + (part[2] + part[3]);
        atomicAdd(loss, tot * (1.25f / 16777216.f));
    }
}

extern "C" void kernel_launch(void* const* d_in, const int* in_sizes, int n_in,
                              void* d_out, int out_size, void* d_ws, size_t ws_size,
                              hipStream_t stream) {
    const float* x = (const float*)d_in[0];
    const float* w = (const float*)d_in[1];

    float* qout = (float*)d_out;
    float* iout = qout + QELEMS;
    float* loss = iout + NPIX;

    char* wp = (char*)d_ws;
    int*   idx        = (int*)wp;                 wp += (size_t)NPIX * 4;        // 256KB
    float* wsq        = (float*)wp;               wp += (size_t)NUM_K * 4;       // 4KB
    float* xsq        = (float*)wp;               wp += (size_t)NPIX * 4;        // 256KB
    int*   flags      = (int*)wp;                 wp += (size_t)MAX_FLAGS * 4;   // 64KB
    int*   flag_count = (int*)wp;                 wp += 256;
    float* wtr        = (float*)wp;               wp += (size_t)NUM_K * DIM * 4; // 1MB
    short* whi        = (short*)wp;               wp += (size_t)NUM_K * DIM * 2; // 512KB
    short* wlo        = (short*)wp;               wp += (size_t)NUM_K * DIM * 2; // 512KB
    float* pd1        = (float*)wp;               wp += (size_t)8 * NPIX * 4;    // 2MB
    float* pd2        = (float*)wp;               wp += (size_t)8 * NPIX * 4;    // 2MB
    int*   pi1        = (int*)wp;                 wp += (size_t)8 * NPIX * 4;    // 2MB
    size_t need = (size_t)(wp - (char*)d_ws);

    hipMemsetAsync(loss, 0, sizeof(float), stream);
    hipMemsetAsync(flag_count, 0, sizeof(int), stream);

    k_wsq<<<4, 256, 0, stream>>>(w, wsq);
    k_xsq<<<NPIX / 256, 256, 0, stream>>>(x, xsq);
    k_wtrans<<<DIM, 1024, 0, stream>>>(w, wtr);

    if (ws_size >= need) {
        k_wfrag<<<128, 256, 0, stream>>>(w, whi, wlo);
        k_argmin_mfma<<<2048, 256, 0, stream>>>(x, whi, wlo, wsq, xsq, pd1, pd2, pi1);
        k_combine<<<NPIX / 256, 256, 0, stream>>>(pd1, pd2, pi1, idx, flags, flag_count);
    } else {
        k_argmin_valu<<<NPIX / 64, 256, 0, stream>>>(x, w, wsq, xsq, idx, flags, flag_count);
    }
    k_refine<<<2048, 1024, 0, stream>>>(x, wtr, wsq, xsq, flags, flag_count, idx);
    k_quant<<<NPIX / 64, 256, 0, stream>>>(x, w, idx, qout, iout, loss);
}